// Round 7
// baseline (155.276 us; speedup 1.0000x reference)
//
#include <hip/hip_runtime.h>

#define NB 16
#define NT 50
#define NA 5
#define NH 152
#define NW 152
#define CH 70             // NA*(7+NC)
#define HW (NH*NW)        // 23104
#define AHW (NA*HW)       // 115520
#define NCELL (NB*AHW)    // 1,848,320
#define NTGT (NB*NT)      // 800

#define NSUMB 452
#define SUM_IT 4          // 452*256*4*4 >= NCELL (bounds-checked)
#define GRID_FUSED (NSUMB + NTGT + 1)   // 1253

// ws float layout (private per-block slots, no atomics anywhere)
#define S_SUM 0                     // 452: softplus grand-total partials
#define S_SUB 452                   // 801: excluded-cell softplus sums
#define S_CNT (S_SUB + 801)         // 801: excluded-cell counts
#define S_WIN (S_CNT + 801)         // 801 x 8: winner loss terms

__device__ __forceinline__ float sp_f(float v) {
    return (v > 20.f) ? v : __logf(1.f + __expf(v));
}

// fully inline; o[0..6]=loss terms, o[7]=count. lab select avoids scratch.
__device__ __forceinline__ void win_terms(const float* __restrict__ xp,
                                          float tx, float ty, float twv, float tlv,
                                          float timv, float trev, int lab,
                                          float* __restrict__ o) {
    float l[14];
    #pragma unroll
    for (int c = 0; c < 14; ++c) l[c] = xp[c * HW];
    float px = 1.f / (1.f + __expf(-l[0]));
    float py = 1.f / (1.f + __expf(-l[1]));
    o[0] = (px - tx) * (px - tx);
    o[1] = (py - ty) * (py - ty);
    float dw = l[2] - twv; o[2] = dw * dw;
    float dh = l[3] - tlv; o[3] = dh * dh;
    float di = l[4] - timv, dr = l[5] - trev;
    o[4] = di * di + dr * dr;
    o[5] = sp_f(-l[6]);
    float mx = l[7];
    #pragma unroll
    for (int c = 8; c < 14; ++c) mx = fmaxf(mx, l[c]);
    float e[7], se = 0.f;
    #pragma unroll
    for (int c = 0; c < 7; ++c) { e[c] = __expf(l[7 + c] - mx); se += e[c]; }
    float se2 = 0.f, slab = 0.f;
    #pragma unroll
    for (int c = 0; c < 7; ++c) {
        float s = e[c] / se;
        se2 += __expf(s);
        if (c == lab) slab = s;     // select, not runtime index
    }
    o[6] = __logf(se2) - slab;
    o[7] = 1.f;
}

__global__ void __launch_bounds__(256) k_fused(const float* __restrict__ x,
                                               const float* __restrict__ tgt,
                                               const float* __restrict__ anc,
                                               float* __restrict__ ws) {
    int tid = threadIdx.x, bx = blockIdx.x;

    // ---------------- role: unmasked grand softplus(l6) sum ----------------
    if (bx < NSUMB) {
        __shared__ float red[256];
        float s = 0.f;
        #pragma unroll
        for (int it = 0; it < SUM_IT; ++it) {
            int c4 = (((it * NSUMB + bx) * 256) + tid) * 4;
            if (c4 < NCELL) {
                int b = c4 / AHW;
                int within = c4 - b * AHW;
                int a = within / HW;
                int rem = within - a * HW;
                const float* p = x + (size_t)(b * CH + a * 14 + 6) * HW + rem;
                float4 v = *(const float4*)p;
                s += sp_f(v.x) + sp_f(v.y) + sp_f(v.z) + sp_f(v.w);
            }
        }
        red[tid] = s;
        __syncthreads();
        for (int st = 128; st > 0; st >>= 1) {
            if (tid < st) red[tid] += red[tid + st];
            __syncthreads();
        }
        if (tid == 0) ws[S_SUM + bx] = red[0];
        return;
    }

    // ---------------- target roles: batch descriptors (phase A) -----------
    __shared__ float s_gx[NT], s_gy[NT], s_gw[NT], s_gl[NT];
    __shared__ float s_xlo[NT], s_xhi[NT], s_ylo[NT], s_yhi[NT], s_q[NT];
    __shared__ float s_tim[NT], s_tre[NT], s_tw[NT], s_tl[NT];
    __shared__ int s_nz[NT], s_valid[NT], s_validp[NT];
    __shared__ int s_gi[NT], s_gj[NT], s_bn[NT], s_am[NT], s_lab[NT];
    __shared__ float s_aw[NA], s_ah[NA];
    __shared__ float redA[256], redB[256];
    __shared__ int s_flag;

    int b = (bx < NSUMB + NTGT) ? (bx - NSUMB) / NT : (NB - 1);

    if (tid < NA) { s_aw[tid] = anc[2 * tid]; s_ah[tid] = anc[2 * tid + 1]; }
    if (tid < NT) {
        const float* tp = tgt + (size_t)(b * NT + tid) * 7;
        float lab = tp[0], cx = tp[1], cy = tp[2], w7 = tp[3], l7 = tp[4];
        float ti = tp[5], tr = tp[6];
        s_nz[tid] = (cx != 0.f) ? 1 : 0;
        s_valid[tid] = ((lab + cx + cy + w7 + l7 + ti + tr) != 0.f) ? 1 : 0;
        float gx = cx * NW, gy = cy * NH, gw = w7 * NW, gl = l7 * NH;
        s_gx[tid] = gx; s_gy[tid] = gy; s_gw[tid] = gw; s_gl[tid] = gl;
        s_xlo[tid] = gx - 0.5f * gw; s_xhi[tid] = gx + 0.5f * gw;
        s_ylo[tid] = gy - 0.5f * gl; s_yhi[tid] = gy + 0.5f * gl;
        s_q[tid] = 0.375f * gw * gl;
        s_gi[tid] = min(max((int)gx, 0), NW - 1);
        s_gj[tid] = min(max((int)gy, 0), NH - 1);
        float agt = (gw + 1.f) * (gl + 1.f);
        float best = -1.f; int bn = 0, am = 0;
        float awb = 1.f, ahb = 1.f;
        for (int a = 0; a < NA; ++a) {
            float aw = anc[2 * a], ah = anc[2 * a + 1];
            float iw = fmaxf(fminf(gw, aw) + 1.f, 0.f);
            float ih = fmaxf(fminf(gl, ah) + 1.f, 0.f);
            float inter = iw * ih;
            float aan = (aw + 1.f) * (ah + 1.f);
            float iou = inter / (agt + aan - inter + 1e-16f);
            if (iou > best) { best = iou; bn = a; awb = aw; ahb = ah; }
            if (iou > 0.6f) am |= (1 << a);
        }
        s_bn[tid] = bn; s_am[tid] = am;
        s_tw[tid] = logf(gw / awb + 1e-16f);
        s_tl[tid] = logf(gl / ahb + 1e-16f);
        s_tim[tid] = ti; s_tre[tid] = tr;
        s_lab[tid] = ((int)lab) & 7;
    }
    __syncthreads();
    if (tid < NT) {
        int vp = 1;
        for (int u = 0; u <= tid; ++u) vp &= s_nz[u];
        s_validp[tid] = vp;
    }
    __syncthreads();

    // exclusion predicate E_u(cell). Fully inline; each USE below is its own
    // site, but the owner-dedup uses exactly ONE site (the first-excluder
    // loop), so ownership is evaluated by identical machine code everywhere.
    auto excl = [&](float bxlo, float bxhi, float bylo, float byhi,
                    float bw, float bh, float qb, int i, int j, int a,
                    int u) -> bool {
        if (s_valid[u] && i == s_gi[u] && j == s_gj[u] &&
            (a == s_bn[u] || ((s_am[u] >> a) & 1))) return true;
        if (s_validp[u]) {
            float mx = fminf(bxlo, s_xlo[u]), Mx = fmaxf(bxhi, s_xhi[u]);
            float my = fminf(bylo, s_ylo[u]), My = fmaxf(byhi, s_yhi[u]);
            float cw = bw + s_gw[u] - (Mx - mx);
            float ch = bh + s_gl[u] - (My - my);
            // iou > 0.6  <=>  carea > 0.375*(area_b + area_g)
            if (cw > 0.f && ch > 0.f && cw * ch > qb + s_q[u]) return true;
        }
        return false;
    };

    if (bx < NSUMB + NTGT) {
        int w = bx - NSUMB;
        int t = w - b * NT;

        // ---- winner eval (merged; integer-exact dedup, last-t-wins) ----
        if (tid == 0) s_flag = 0;
        __syncthreads();
        if (s_valid[t]) {
            int t2 = t + 1 + tid;
            if (t2 < NT && s_valid[t2] &&
                s_gi[t2] == s_gi[t] && s_gj[t2] == s_gj[t] && s_bn[t2] == s_bn[t])
                s_flag = 1;   // benign monotone race
        }
        __syncthreads();
        if (tid == 0) {
            float slot[8] = {0.f, 0.f, 0.f, 0.f, 0.f, 0.f, 0.f, 0.f};
            if (s_valid[t] && !s_flag) {
                const float* xp = x + (size_t)(b * CH + s_bn[t] * 14) * HW
                                  + s_gj[t] * NW + s_gi[t];
                win_terms(xp, s_gx[t] - (float)s_gi[t], s_gy[t] - (float)s_gj[t],
                          s_tw[t], s_tl[t], s_tim[t], s_tre[t], s_lab[t], slot);
            }
            float* dst = ws + S_WIN + w * 8;
            #pragma unroll
            for (int k = 0; k < 8; ++k) dst[k] = slot[k];
        }

        // ---- owner-subtract over the target's reach rect ----
        float sub = 0.f, cnt = 0.f;
        int i_lo = 1, i_hi = 0, j_lo = 1, j_hi = 0;   // empty sentinel
        bool vp = s_validp[t] && s_gw[t] > 0.f && s_gl[t] > 0.f;
        if (vp) {
            // proven reach: IoU pass => |bx-gx| < gw/3, |by-gy| < gl/3 (+1 margin)
            float gw3 = s_gw[t] * (1.f / 3.f), gl3 = s_gl[t] * (1.f / 3.f);
            i_lo = max(0, (int)floorf(s_gx[t] - gw3) - 1);
            i_hi = min(NW - 1, (int)floorf(s_gx[t] + gw3) + 1);
            j_lo = max(0, (int)floorf(s_gy[t] - gl3) - 1);
            j_hi = min(NH - 1, (int)floorf(s_gy[t] + gl3) + 1);
            int W = i_hi - i_lo + 1, Hh = j_hi - j_lo + 1;
            int total = W * Hh * NA;
            for (int idx = tid; idx < total; idx += 256) {
                int dx = idx % W;
                int q2 = idx / W;
                int j = j_lo + q2 % Hh;
                int a = q2 / Hh;
                int i = i_lo + dx;
                const float* xp = x + (size_t)(b * CH + a * 14) * HW + j * NW + i;
                float l0 = xp[0], l1 = xp[HW], l2 = xp[2 * HW], l3 = xp[3 * HW];
                float l6v = xp[6 * HW];
                float bxv = (float)i + 1.f / (1.f + __expf(-l0));
                float byv = (float)j + 1.f / (1.f + __expf(-l1));
                float bw = __expf(l2) * s_aw[a], bh = __expf(l3) * s_ah[a];
                float bxlo = bxv - 0.5f * bw, bxhi = bxv + 0.5f * bw;
                float bylo = byv - 0.5f * bh, byhi = byv + 0.5f * bh;
                float qb = 0.375f * bw * bh;
                // single-site first-excluder loop: owner iff first hit == t
                int firstu = -1;
                for (int u = 0; u <= t; ++u) {
                    if (excl(bxlo, bxhi, bylo, byhi, bw, bh, qb, i, j, a, u)) {
                        firstu = u; break;
                    }
                }
                if (firstu == t) { sub += sp_f(l6v); cnt += 1.f; }
            }
        }
        // fallback: override cells outside the rect (only if valid && !vp,
        // which cannot occur with suffix-zero padding; kept for safety)
        if (tid == 0 && s_valid[t] && !vp) {
            int gi = s_gi[t], gj = s_gj[t];
            for (int a = 0; a < NA; ++a) {
                if (a == s_bn[t] || ((s_am[t] >> a) & 1)) {
                    const float* xp = x + (size_t)(b * CH + a * 14) * HW + gj * NW + gi;
                    float l0 = xp[0], l1 = xp[HW], l2 = xp[2 * HW], l3 = xp[3 * HW];
                    float l6v = xp[6 * HW];
                    float bxv = (float)gi + 1.f / (1.f + __expf(-l0));
                    float byv = (float)gj + 1.f / (1.f + __expf(-l1));
                    float bw = __expf(l2) * s_aw[a], bh = __expf(l3) * s_ah[a];
                    float bxlo = bxv - 0.5f * bw, bxhi = bxv + 0.5f * bw;
                    float bylo = byv - 0.5f * bh, byhi = byv + 0.5f * bh;
                    float qb = 0.375f * bw * bh;
                    int firstu = -1;
                    for (int u = 0; u <= t; ++u) {
                        if (excl(bxlo, bxhi, bylo, byhi, bw, bh, qb, gi, gj, a, u)) {
                            firstu = u; break;
                        }
                    }
                    if (firstu == t) { sub += sp_f(l6v); cnt += 1.f; }
                }
            }
        }
        redA[tid] = sub; redB[tid] = cnt;
        __syncthreads();
        for (int st = 128; st > 0; st >>= 1) {
            if (tid < st) { redA[tid] += redA[tid + st]; redB[tid] += redB[tid + st]; }
            __syncthreads();
        }
        if (tid == 0) { ws[S_SUB + w] = redA[0]; ws[S_CNT + w] = redB[0]; }
    } else {
        // ---------------- role: c* (np negative-index wrap cell) -----------
        if (tid == 0) s_flag = 0;
        __syncthreads();
        for (int id = tid; id < NTGT; id += 256) {
            const float* tp = tgt + (size_t)id * 7;
            float s7 = tp[0] + tp[1] + tp[2] + tp[3] + tp[4] + tp[5] + tp[6];
            if (s7 == 0.f) s_flag = 1;   // any invalid row -> wrap writes exist
        }
        __syncthreads();
        if (tid == 0) {
            float slot[8] = {0.f, 0.f, 0.f, 0.f, 0.f, 0.f, 0.f, 0.f};
            float sub = 0.f, cnt = 0.f;
            if (s_flag) {
                // winner values from an all-zero row: tx=ty=tim=tre=0,
                // tw=tl=log(1e-16), label 0
                const float* xp = x + (size_t)((NB - 1) * CH + (NA - 1) * 14) * HW
                                  + (HW - 1);
                float L16 = logf(1e-16f);
                win_terms(xp, 0.f, 0.f, L16, L16, 0.f, 0.f, 0, slot);
                // subtract c* unless some batch-15 target already excludes it
                int i = NW - 1, j = NH - 1, a = NA - 1;
                float l0 = xp[0], l1 = xp[HW], l2 = xp[2 * HW], l3 = xp[3 * HW];
                float l6v = xp[6 * HW];
                float bxv = (float)i + 1.f / (1.f + __expf(-l0));
                float byv = (float)j + 1.f / (1.f + __expf(-l1));
                float bw = __expf(l2) * s_aw[a], bh = __expf(l3) * s_ah[a];
                float bxlo = bxv - 0.5f * bw, bxhi = bxv + 0.5f * bw;
                float bylo = byv - 0.5f * bh, byhi = byv + 0.5f * bh;
                float qb = 0.375f * bw * bh;
                bool any = false;
                for (int u = 0; u < NT; ++u)
                    if (excl(bxlo, bxhi, bylo, byhi, bw, bh, qb, i, j, a, u)) {
                        any = true; break;
                    }
                if (!any) { sub = sp_f(l6v); cnt = 1.f; }
            }
            float* dst = ws + S_WIN + NTGT * 8;
            #pragma unroll
            for (int k = 0; k < 8; ++k) dst[k] = slot[k];
            ws[S_SUB + NTGT] = sub;
            ws[S_CNT + NTGT] = cnt;
        }
    }
}

// ---------------- tiny deterministic reduce + loss assembly ----------------
__global__ void __launch_bounds__(256) k_reduce2(const float* __restrict__ ws,
                                                 float* __restrict__ out) {
    int tid = threadIdx.x;
    double acc[11];
    #pragma unroll
    for (int k = 0; k < 11; ++k) acc[k] = 0.0;
    for (int s = tid; s < NTGT + 1; s += 256) {
        const float* p = ws + S_WIN + s * 8;
        #pragma unroll
        for (int k = 0; k < 8; ++k) acc[k] += (double)p[k];
        acc[8] += (double)ws[S_SUB + s];
        acc[9] += (double)ws[S_CNT + s];
    }
    for (int s = tid; s < NSUMB; s += 256) acc[10] += (double)ws[S_SUM + s];

    __shared__ double R[11][256];
    #pragma unroll
    for (int k = 0; k < 11; ++k) R[k][tid] = acc[k];
    __syncthreads();
    for (int st = 128; st > 0; st >>= 1) {
        if (tid < st) {
            #pragma unroll
            for (int k = 0; k < 11; ++k) R[k][tid] += R[k][tid + st];
        }
        __syncthreads();
    }
    if (tid == 0) {
        double nM  = fmax(R[7][0], 1.0);
        double scf = fmax((double)NCELL - R[9][0], 1.0);
        double bce = R[10][0] - R[8][0];
        double loss =
            (R[0][0] + R[1][0] + R[2][0] + R[3][0] + R[4][0] + R[5][0]) / nM
            + bce / scf
            + (1.0 / NB) * R[6][0] / nM;
        out[0] = (float)loss;
    }
}

extern "C" void kernel_launch(void* const* d_in, const int* in_sizes, int n_in,
                              void* d_out, int out_size, void* d_ws, size_t ws_size,
                              hipStream_t stream) {
    const float* x   = (const float*)d_in[0];
    const float* tgt = (const float*)d_in[1];
    const float* anc = (const float*)d_in[2];
    float* ws  = (float*)d_ws;
    float* out = (float*)d_out;

    hipLaunchKernelGGL(k_fused, dim3(GRID_FUSED), dim3(256), 0, stream,
                       x, tgt, anc, ws);
    hipLaunchKernelGGL(k_reduce2, dim3(1), dim3(256), 0, stream, ws, out);
}

// Round 8
// 32.973 us; speedup vs baseline: 4.7093x; 4.7093x over previous
//
#include <hip/hip_runtime.h>

#define NB 16
#define NT 50
#define NA 5
#define NH 152
#define NW 152
#define CH 70             // NA*(7+NC)
#define HW (NH*NW)        // 23104
#define AHW (NA*HW)       // 115520
#define NCELL (NB*AHW)    // 1,848,320
#define NTGT (NB*NT)      // 800

#define NSUMB 452
#define SUM_IT 4          // 452*256*4*4 >= NCELL (bounds-checked)
#define GRID_FUSED (NSUMB + NTGT + 1)   // 1253
#define CAP 2944          // >= max rect 24*24*5 + NA

// ws float layout (private per-block slots, no atomics anywhere)
#define S_SUM 0                     // 452: softplus grand-total partials
#define S_SUB 452                   // 801: excluded-cell softplus sums
#define S_CNT (S_SUB + 801)         // 801: excluded-cell counts
#define S_WIN (S_CNT + 801)         // 801 x 8: winner loss terms

__device__ __forceinline__ float sp_f(float v) {
    return (v > 20.f) ? v : __logf(1.f + __expf(v));
}

struct Box { float xlo, xhi, ylo, yhi, w, h, qb; };

// contract(off): bit-identical at every inline site (ownership dedup needs
// cross-block agreement; FMA contraction is the only cross-site hazard).
__device__ __forceinline__ Box build_box(const float* __restrict__ xp,
                                         float aw, float ah, int i, int j) {
    #pragma clang fp contract(off)
    float l0 = xp[0], l1 = xp[HW], l2 = xp[2 * HW], l3 = xp[3 * HW];
    float sx = 1.f / (1.f + __expf(-l0));
    float sy = 1.f / (1.f + __expf(-l1));
    float bxv = (float)i + sx;
    float byv = (float)j + sy;
    float bw = __expf(l2) * aw, bh = __expf(l3) * ah;
    float hw2 = 0.5f * bw, hh2 = 0.5f * bh;
    Box o;
    o.xlo = bxv - hw2; o.xhi = bxv + hw2;
    o.ylo = byv - hh2; o.yhi = byv + hh2;
    o.w = bw; o.h = bh; o.qb = 0.375f * bw * bh;
    return o;
}

__device__ __forceinline__ bool excl_eval(const Box& bb, int i, int j, int a,
                                          int valid, int validp,
                                          int gi, int gj, int bn, int am,
                                          float xlo, float xhi, float ylo, float yhi,
                                          float gw, float gl, float q) {
    #pragma clang fp contract(off)
    if (valid && i == gi && j == gj && (a == bn || ((am >> a) & 1))) return true;
    if (validp) {
        float mx = fminf(bb.xlo, xlo), Mx = fmaxf(bb.xhi, xhi);
        float my = fminf(bb.ylo, ylo), My = fmaxf(bb.yhi, yhi);
        float cw = bb.w + gw - (Mx - mx);
        float ch = bb.h + gl - (My - my);
        // iou > 0.6  <=>  carea > 0.375*(area_b + area_g)
        if (cw > 0.f && ch > 0.f && cw * ch > bb.qb + q) return true;
    }
    return false;
}

// o[0..6]=loss terms, o[7]=count; lab via select (no scratch)
__device__ __forceinline__ void win_terms(const float* __restrict__ xp,
                                          float tx, float ty, float twv, float tlv,
                                          float timv, float trev, int lab,
                                          float* __restrict__ o) {
    float l[14];
    #pragma unroll
    for (int c = 0; c < 14; ++c) l[c] = xp[c * HW];
    float px = 1.f / (1.f + __expf(-l[0]));
    float py = 1.f / (1.f + __expf(-l[1]));
    o[0] = (px - tx) * (px - tx);
    o[1] = (py - ty) * (py - ty);
    float dw = l[2] - twv; o[2] = dw * dw;
    float dh = l[3] - tlv; o[3] = dh * dh;
    float di = l[4] - timv, dr = l[5] - trev;
    o[4] = di * di + dr * dr;
    o[5] = sp_f(-l[6]);
    float mx = l[7];
    #pragma unroll
    for (int c = 8; c < 14; ++c) mx = fmaxf(mx, l[c]);
    float e[7], se = 0.f;
    #pragma unroll
    for (int c = 0; c < 7; ++c) { e[c] = __expf(l[7 + c] - mx); se += e[c]; }
    float se2 = 0.f, slab = 0.f;
    #pragma unroll
    for (int c = 0; c < 7; ++c) {
        float s = e[c] / se;
        se2 += __expf(s);
        if (c == lab) slab = s;
    }
    o[6] = __logf(se2) - slab;
    o[7] = 1.f;
}

__global__ void __launch_bounds__(256) k_fused(const float* __restrict__ x,
                                               const float* __restrict__ tgt,
                                               const float* __restrict__ anc,
                                               float* __restrict__ ws) {
    __shared__ float redA[256], redB[256];
    int tid = threadIdx.x, bx = blockIdx.x;

    // ---------------- role: unmasked grand softplus(l6) sum ----------------
    if (bx < NSUMB) {
        float s = 0.f;
        for (int it = 0; it < SUM_IT; ++it) {
            int c4 = (((it * NSUMB + bx) * 256) + tid) * 4;
            if (c4 < NCELL) {
                int b = c4 / AHW;
                int within = c4 - b * AHW;
                int a = within / HW;
                int rem = within - a * HW;
                const float* p = x + (size_t)(b * CH + a * 14 + 6) * HW + rem;
                float4 v = *(const float4*)p;
                s += sp_f(v.x) + sp_f(v.y) + sp_f(v.z) + sp_f(v.w);
            }
        }
        redA[tid] = s;
        __syncthreads();
        for (int st = 128; st > 0; st >>= 1) {
            if (tid < st) redA[tid] += redA[tid + st];
            __syncthreads();
        }
        if (tid == 0) ws[S_SUM + bx] = redA[0];
        return;
    }

    // ---------------- owner/winner blocks (incl. c* pseudo-target) ---------
    __shared__ float s_gx[NT + 1], s_gy[NT + 1], s_gw[NT + 1], s_gl[NT + 1];
    __shared__ float s_xlo[NT + 1], s_xhi[NT + 1], s_ylo[NT + 1], s_yhi[NT + 1];
    __shared__ float s_q[NT + 1], s_tim[NT], s_tre[NT], s_tw[NT], s_tl[NT];
    __shared__ int s_nz[NT], s_valid[NT + 1], s_validp[NT + 1];
    __shared__ int s_gi[NT + 1], s_gj[NT + 1], s_bn[NT + 1], s_am[NT + 1], s_lab[NT];
    __shared__ float s_aw[NA], s_ah[NA];
    __shared__ int s_stack[CAP];
    __shared__ int s_n, s_wrap, s_dup;

    int w = bx - NSUMB;                       // 0..800
    bool isC = (w == NTGT);
    int b = isC ? (NB - 1) : (w / NT);
    int t = isC ? NT : (w - b * NT);

    // -------- region 1: descriptors + inits --------
    if (tid < NA) { s_aw[tid] = anc[2 * tid]; s_ah[tid] = anc[2 * tid + 1]; }
    if (tid == 0) { s_n = 0; s_wrap = 0; s_dup = 0; }
    if (tid < NT) {
        const float* tp = tgt + (size_t)(b * NT + tid) * 7;
        float lab = tp[0], cx = tp[1], cy = tp[2], w7 = tp[3], l7 = tp[4];
        float ti = tp[5], tr = tp[6];
        s_nz[tid] = (cx != 0.f) ? 1 : 0;
        s_valid[tid] = ((lab + cx + cy + w7 + l7 + ti + tr) != 0.f) ? 1 : 0;
        float gx = cx * NW, gy = cy * NH, gw = w7 * NW, gl = l7 * NH;
        s_gx[tid] = gx; s_gy[tid] = gy; s_gw[tid] = gw; s_gl[tid] = gl;
        s_xlo[tid] = gx - 0.5f * gw; s_xhi[tid] = gx + 0.5f * gw;
        s_ylo[tid] = gy - 0.5f * gl; s_yhi[tid] = gy + 0.5f * gl;
        s_q[tid] = 0.375f * gw * gl;
        s_gi[tid] = min(max((int)gx, 0), NW - 1);
        s_gj[tid] = min(max((int)gy, 0), NH - 1);
        float agt = (gw + 1.f) * (gl + 1.f);
        float best = -1.f; int bn = 0, am = 0;
        float awb = 1.f, ahb = 1.f;
        for (int a = 0; a < NA; ++a) {
            float aw = anc[2 * a], ah = anc[2 * a + 1];
            float iw = fmaxf(fminf(gw, aw) + 1.f, 0.f);
            float ih = fmaxf(fminf(gl, ah) + 1.f, 0.f);
            float inter = iw * ih;
            float aan = (aw + 1.f) * (ah + 1.f);
            float iou = inter / (agt + aan - inter + 1e-16f);
            if (iou > best) { best = iou; bn = a; awb = aw; ahb = ah; }
            if (iou > 0.6f) am |= (1 << a);
        }
        s_bn[tid] = bn; s_am[tid] = am;
        s_tw[tid] = logf(gw / awb + 1e-16f);
        s_tl[tid] = logf(gl / ahb + 1e-16f);
        s_tim[tid] = ti; s_tre[tid] = tr;
        s_lab[tid] = ((int)lab) & 7;
    }
    __syncthreads();

    // -------- region 2: prefix validp, wrap scan, winner-dup scan --------
    if (tid < NT) {
        int vp = 1;
        for (int u = 0; u <= tid; ++u) vp &= s_nz[u];
        s_validp[tid] = vp;
    }
    if (isC) {
        for (int id = tid; id < NTGT; id += 256) {
            const float* tp = tgt + (size_t)id * 7;
            float s7 = tp[0] + tp[1] + tp[2] + tp[3] + tp[4] + tp[5] + tp[6];
            if (s7 == 0.f) s_wrap = 1;      // benign monotone race
        }
    } else if (s_valid[t]) {
        int t2 = t + 1 + tid;
        if (t2 < NT && s_valid[t2] &&
            s_gi[t2] == s_gi[t] && s_gj[t2] == s_gj[t] && s_bn[t2] == s_bn[t])
            s_dup = 1;                       // benign monotone race
    }
    __syncthreads();

    // -------- region 3: c* pseudo-descriptor (index NT) --------
    if (tid == 0) {
        s_valid[NT] = isC ? s_wrap : 0;
        s_validp[NT] = 0;
        s_gi[NT] = NW - 1; s_gj[NT] = NH - 1; s_bn[NT] = NA - 1; s_am[NT] = 0;
        s_gx[NT] = 0.f; s_gy[NT] = 0.f; s_gw[NT] = 0.f; s_gl[NT] = 0.f;
        s_xlo[NT] = 0.f; s_xhi[NT] = 0.f; s_ylo[NT] = 0.f; s_yhi[NT] = 0.f;
        s_q[NT] = 0.f;
    }
    __syncthreads();

    // -------- region 4: winner slot write (tid 0) + phase-1 rect scan ------
    if (tid == 0) {
        float slot[8] = {0.f, 0.f, 0.f, 0.f, 0.f, 0.f, 0.f, 0.f};
        if (isC) {
            if (s_wrap) {
                const float* xp = x + (size_t)((NB - 1) * CH + (NA - 1) * 14) * HW
                                  + (HW - 1);
                float L16 = logf(1e-16f);
                win_terms(xp, 0.f, 0.f, L16, L16, 0.f, 0.f, 0, slot);
            }
        } else if (s_valid[t] && !s_dup) {   // last-t-wins (np scatter order)
            const float* xp = x + (size_t)(b * CH + s_bn[t] * 14) * HW
                              + s_gj[t] * NW + s_gi[t];
            win_terms(xp, s_gx[t] - (float)s_gi[t], s_gy[t] - (float)s_gj[t],
                      s_tw[t], s_tl[t], s_tim[t], s_tre[t], s_lab[t], slot);
        }
        float* dst = ws + S_WIN + w * 8;
        #pragma unroll
        for (int k = 0; k < 8; ++k) dst[k] = slot[k];
    }

    // phase 1: E_t only (1 eval/cell), push hits to LDS stack
    bool vp = s_validp[t] && s_gw[t] > 0.f && s_gl[t] > 0.f;
    int i_lo = 0, j_lo = 0, W = 0, Hh = 0, rectTotal = 0;
    if (vp) {
        // proven reach: IoU pass => |bx-gx| < gw/3, |by-gy| < gl/3 (+1 margin)
        float gw3 = s_gw[t] * (1.f / 3.f), gl3 = s_gl[t] * (1.f / 3.f);
        i_lo = max(0, (int)floorf(s_gx[t] - gw3) - 1);
        int i_hi = min(NW - 1, (int)floorf(s_gx[t] + gw3) + 1);
        j_lo = max(0, (int)floorf(s_gy[t] - gl3) - 1);
        int j_hi = min(NH - 1, (int)floorf(s_gy[t] + gl3) + 1);
        W = i_hi - i_lo + 1; Hh = j_hi - j_lo + 1;
        rectTotal = W * Hh * NA;
    }
    int extra = (s_valid[t] && !vp) ? NA : 0;   // override cells (c*; safety)
    int total = rectTotal + extra;
    for (int idx = tid; idx < total; idx += 256) {
        int i, j, a;
        if (idx < rectTotal) {
            int dx = idx % W;
            int q2 = idx / W;
            j = j_lo + q2 % Hh;
            a = q2 / Hh;
            i = i_lo + dx;
        } else {
            a = idx - rectTotal; i = s_gi[t]; j = s_gj[t];
            if (!(a == s_bn[t] || ((s_am[t] >> a) & 1))) continue;
        }
        const float* xp = x + (size_t)(b * CH + a * 14) * HW + j * NW + i;
        Box bb = build_box(xp, s_aw[a], s_ah[a], i, j);
        if (excl_eval(bb, i, j, a, s_valid[t], s_validp[t],
                      s_gi[t], s_gj[t], s_bn[t], s_am[t],
                      s_xlo[t], s_xhi[t], s_ylo[t], s_yhi[t],
                      s_gw[t], s_gl[t], s_q[t])) {
            int pos = atomicAdd(&s_n, 1);
            if (pos < CAP) s_stack[pos] = (a << 16) | (j << 8) | i;
        }
    }
    __syncthreads();

    // -------- phase 2: compacted dedup scan (owner iff no u<t excludes) ----
    int n = min(s_n, CAP);
    float sub = 0.f, cnt = 0.f;
    for (int k = tid; k < n; k += 256) {
        int pk = s_stack[k];
        int i = pk & 255, j = (pk >> 8) & 255, a = pk >> 16;
        const float* xp = x + (size_t)(b * CH + a * 14) * HW + j * NW + i;
        Box bb = build_box(xp, s_aw[a], s_ah[a], i, j);
        bool owned = true;
        for (int u = 0; u < t; ++u) {
            if (excl_eval(bb, i, j, a, s_valid[u], s_validp[u],
                          s_gi[u], s_gj[u], s_bn[u], s_am[u],
                          s_xlo[u], s_xhi[u], s_ylo[u], s_yhi[u],
                          s_gw[u], s_gl[u], s_q[u])) { owned = false; break; }
        }
        if (owned) {
            sub += sp_f(xp[6 * HW]);
            cnt += 1.f;
        }
    }
    redA[tid] = sub; redB[tid] = cnt;
    __syncthreads();
    for (int st = 128; st > 0; st >>= 1) {
        if (tid < st) { redA[tid] += redA[tid + st]; redB[tid] += redB[tid + st]; }
        __syncthreads();
    }
    if (tid == 0) { ws[S_SUB + w] = redA[0]; ws[S_CNT + w] = redB[0]; }
}

// ---------------- tiny deterministic reduce + loss assembly ----------------
__global__ void __launch_bounds__(256) k_reduce2(const float* __restrict__ ws,
                                                 float* __restrict__ out) {
    int tid = threadIdx.x;
    double acc[11];
    #pragma unroll
    for (int k = 0; k < 11; ++k) acc[k] = 0.0;
    for (int s = tid; s < NTGT + 1; s += 256) {
        const float* p = ws + S_WIN + s * 8;
        #pragma unroll
        for (int k = 0; k < 8; ++k) acc[k] += (double)p[k];
        acc[8] += (double)ws[S_SUB + s];
        acc[9] += (double)ws[S_CNT + s];
    }
    for (int s = tid; s < NSUMB; s += 256) acc[10] += (double)ws[S_SUM + s];

    __shared__ double R[11][256];
    #pragma unroll
    for (int k = 0; k < 11; ++k) R[k][tid] = acc[k];
    __syncthreads();
    for (int st = 128; st > 0; st >>= 1) {
        if (tid < st) {
            #pragma unroll
            for (int k = 0; k < 11; ++k) R[k][tid] += R[k][tid + st];
        }
        __syncthreads();
    }
    if (tid == 0) {
        double nM  = fmax(R[7][0], 1.0);
        double scf = fmax((double)NCELL - R[9][0], 1.0);
        double bce = R[10][0] - R[8][0];
        double loss =
            (R[0][0] + R[1][0] + R[2][0] + R[3][0] + R[4][0] + R[5][0]) / nM
            + bce / scf
            + (1.0 / NB) * R[6][0] / nM;
        out[0] = (float)loss;
    }
}

extern "C" void kernel_launch(void* const* d_in, const int* in_sizes, int n_in,
                              void* d_out, int out_size, void* d_ws, size_t ws_size,
                              hipStream_t stream) {
    const float* x   = (const float*)d_in[0];
    const float* tgt = (const float*)d_in[1];
    const float* anc = (const float*)d_in[2];
    float* ws  = (float*)d_ws;
    float* out = (float*)d_out;

    hipLaunchKernelGGL(k_fused, dim3(GRID_FUSED), dim3(256), 0, stream,
                       x, tgt, anc, ws);
    hipLaunchKernelGGL(k_reduce2, dim3(1), dim3(256), 0, stream, ws, out);
}